// Round 11
// baseline (903.895 us; speedup 1.0000x reference)
//
#include <hip/hip_runtime.h>

// DeepRLSNet: batched RLS. B=64, N=T=2000, TAPS=64.
//
// R23 = R19/R22 structure with a HOMOGENEOUS 512-thread split: thread
// (r = tid>>3, q8 = tid&7) owns 8 columns [8*q8, 8*q8+8) of row r of Q,QT
// (vs 16 columns at 256 threads). Per-wave issue halves; 8 waves = 2/SIMD
// give each SIMD a second identical-role independent stream to fill the
// dependency-bubble stall (~970cy/round) that R13..R22 proved irreducible
// at 1 wave/SIMD. NOT R14's heterogeneous split: no duplicated post-barrier
// work, exchange volume/barrier count/LDS layout unchanged.
//
// NUMERICS: dot reductions re-associate (8 lanes x 8-col chains vs 4 x 16).
// This is the first NON-bit-identical change: justified because (a) the
// test threshold is 0.13375 and our absmax 0.015625 is output-bf16-
// quantization-dominated (8.5x headroom), and (b) the load-bearing
// QT==Q^T invariant (R10/R11 bisect) survives ANY reduction order: dual
// rank-1 updates use shared broadcast scalars and sign-symmetric products
// ((-a)*b == a*(-b) bitwise). Expect absmax ~0.0156, must be < 0.13375.
//
// oct_reduce: fused v_add_f32_dpp (R22's proven s_nop-guarded pattern),
// stages xor1, xor2, row_half_mirror (= xor7 inside each 8-lane group;
// 8-aligned groups never cross the 8-lane halves). All lanes get
// bitwise-identical sums (IEEE add commutes).

#define B_ 64
#define N_ 2000
#define TAPS_ 64
#define STEPS_ 2000
#define VST_ 72   // padded LDS vector stride (write banks (8v+r)%32: 32 distinct)

typedef float f2 __attribute__((ext_vector_type(2)));

__device__ __forceinline__ f2 pk2(float v) { f2 r; r.x = v; r.y = v; return r; }

__device__ __forceinline__ void lds_barrier() {
    // LDS-only fence + barrier: global (vmcnt) prefetch stays in flight.
    asm volatile("s_waitcnt lgkmcnt(0)\n\ts_barrier" ::: "memory");
}

__device__ __forceinline__ float clipl(float v) {
    return fminf(fmaxf(v, 1e-4f), 0.9999f);
}

// sum over the 8 q8-lanes of an (8-aligned) lane group. Fused DPP adds with
// explicit 2-wait-state hazard guards (R22 pattern, verified on HW).
//   stage1: xor1 (quad_perm), stage2: xor2 (quad_perm),
//   stage3: row_half_mirror = lane i -> i^7 within each 8-lane half:
//           adds the other quad's total; all 8 lanes identical bits.
__device__ __forceinline__ float oct_reduce(float v) {
    float r;
    asm("s_nop 1\n\t"
        "v_add_f32_dpp %0, %1, %1 quad_perm:[1,0,3,2] row_mask:0xf bank_mask:0xf\n\t"
        "s_nop 1\n\t"
        "v_add_f32_dpp %0, %0, %0 quad_perm:[2,3,0,1] row_mask:0xf bank_mask:0xf\n\t"
        "s_nop 1\n\t"
        "v_add_f32_dpp %0, %0, %0 row_half_mirror row_mask:0xf bank_mask:0xf"
        : "=&v"(r) : "v"(v));
    return r;
}

// 1/v via v_rcp_f32 + one Newton step (~0.5 ulp). Identical to R19.
__device__ __forceinline__ float rcp_nr(float v) {
    float r = __builtin_amdgcn_rcpf(v);
    float e = fmaf(-v, r, 1.0f);
    return fmaf(r, e, r);
}

__global__ __launch_bounds__(512, 2) void rls_kernel(
    const float* __restrict__ x_seq,   // [B, N, TAPS]
    const float* __restrict__ d_seq,   // [B, N]
    const float* __restrict__ lambdas, // [T]
    float* __restrict__ y_out,         // [B, N]
    float* __restrict__ w_out)         // [B, TAPS]
{
    const int b   = blockIdx.x;
    const int tid = threadIdx.x;      // 0..511
    const int r   = tid >> 3;         // row 0..63
    const int q8  = tid & 7;          // eighth 0..7
    const int cb  = q8 << 3;          // column base

    // [parity][vec][VST_], vec: 0=Qx 1=xQ 2=u 3=v  (R12 layout, unchanged)
    __shared__ __align__(16) float  bufs[2][4][VST_];
    __shared__ __align__(16) float  d_lds[STEPS_];
    __shared__ __align__(16) float2 lam2[STEPS_];   // {clip(lam), rcp_nr(clip(lam))}

    const float* xb = x_seq + (size_t)b * N_ * TAPS_;
    const float* db = d_seq + (size_t)b * N_;

    for (int idx = tid; idx < STEPS_; idx += 512) {
        d_lds[idx] = db[idx];
        const float lc = clipl(lambdas[idx]);
        lam2[idx] = make_float2(lc, rcp_nr(lc));
    }

    // state: 8-column slices (4 f2) of row r of Q, QT; w slice replicated
    // across the 64 row groups.
    f2 Q[4], QT[4], w[4];
    #pragma unroll
    for (int j = 0; j < 4; ++j) {
        Q[j].x = (cb + 2*j     == r) ? 1.0f : 0.0f;
        Q[j].y = (cb + 2*j + 1 == r) ? 1.0f : 0.0f;
        QT[j] = Q[j];
        w[j]  = pk2(0.0f);
    }
    float sig = 1.0f;   // P = sig * Q

    auto unpack4 = [](f2* dst, float4 v) {
        dst[0].x = v.x; dst[0].y = v.y; dst[1].x = v.z; dst[1].y = v.w;
    };

    auto loadpair = [&](f2 (&dA)[4], f2 (&dB)[4], int row) {
        const float4* v0 = (const float4*)(xb + (size_t)row * TAPS_ + cb);
        const float4* v1 = (const float4*)(xb + (size_t)(row + 1) * TAPS_ + cb);
        #pragma unroll
        for (int j4 = 0; j4 < 2; ++j4) {
            unpack4(&dA[2*j4], v0[j4]);
            unpack4(&dB[2*j4], v1[j4]);
        }
    };

    // 4 rotating row-pairs (R15 rotation). Round k: x=pair k&3, xn=(k+1)&3,
    // prefetch rows t+6,t+7 into pair (k+3)&3.
    f2 P0a[4], P0b[4], P1a[4], P1b[4], P2a[4], P2b[4], P3a[4], P3b[4];
    loadpair(P0a, P0b, 0);
    loadpair(P1a, P1b, 2);
    loadpair(P2a, P2b, 4);

    // loop-carried reduced row values (produced by prologue / fused phase).
    float qxrS, xqrS, urS, vrS, wy0S, wy1S;

    // ---- prologue: round 0's exchange data (R19 pre-phase, 8-col chains) ----
    {
        f2 qx2 = pk2(0.f), xq2 = pk2(0.f), u2 = pk2(0.f), v2 = pk2(0.f);
        #pragma unroll
        for (int j = 0; j < 4; ++j) {
            qx2 = __builtin_elementwise_fma(Q[j],  P0a[j], qx2);
            xq2 = __builtin_elementwise_fma(QT[j], P0a[j], xq2);
            u2  = __builtin_elementwise_fma(Q[j],  P0b[j], u2);
            v2  = __builtin_elementwise_fma(QT[j], P0b[j], v2);
        }
        qxrS = oct_reduce(qx2.x + qx2.y);
        xqrS = oct_reduce(xq2.x + xq2.y);
        urS  = oct_reduce(u2.x + u2.y);
        vrS  = oct_reduce(v2.x + v2.y);
        if (q8 < 4)
            bufs[0][q8][r] =
                (q8 == 0) ? qxrS : (q8 == 1) ? xqrS : (q8 == 2) ? urS : vrS;

        f2 wy02 = pk2(0.f), wy12 = pk2(0.f);
        #pragma unroll
        for (int j = 0; j < 4; ++j) {
            wy02 = __builtin_elementwise_fma(w[j], P0a[j], wy02);
            wy12 = __builtin_elementwise_fma(w[j], P0b[j], wy12);
        }
        wy0S = oct_reduce(wy02.x + wy02.y);
        wy1S = oct_reduce(wy12.x + wy12.y);
    }

    auto round = [&](int t, f2 (&x0)[4], f2 (&x1)[4],
                     f2 (&xn0)[4], f2 (&xn1)[4],
                     f2 (&xf0)[4], f2 (&xf1)[4],
                     int par, bool pf, bool fuse)
    {
        lds_barrier();   // exchange data (written last round) visible

        // ---- slice ds_reads up-front: group-1 (Qxq,xQq) first, then
        //      group-2 (uq,vq). 8 b128/lane (half of the 256-thread form);
        //      same-q8 lanes broadcast, distinct addrs 2-way aliased (free).
        f2 Qxq[4], xQq[4], uq[4], vq[4];
        {
            const float4* p0 = (const float4*)(&bufs[par][0][cb]);
            const float4* p1 = (const float4*)(&bufs[par][1][cb]);
            #pragma unroll
            for (int j4 = 0; j4 < 2; ++j4) {
                unpack4(&Qxq[2*j4], p0[j4]);
                unpack4(&xQq[2*j4], p1[j4]);
            }
            const float4* p2 = (const float4*)(&bufs[par][2][cb]);
            const float4* p3 = (const float4*)(&bufs[par][3][cb]);
            #pragma unroll
            for (int j4 = 0; j4 < 2; ++j4) {
                unpack4(&uq[2*j4], p2[j4]);
                unpack4(&vq[2*j4], p3[j4]);
            }
        }
        // lam pair fused to one b128 (t even -> 16B aligned).
        const float4 lf = *(const float4*)&lam2[t];   // {l0.x,l0.y,l1.x,l1.y}
        const float2 dd = *(const float2*)&d_lds[t];

        // ---- deep prefetch (global pipe; rides across barriers) ----
        if (pf) loadpair(xf0, xf1, t + 6);

        // ---- pd chain first, then den0->rcp->s0 early (overlaps a/bb/c2) ----
        f2 pd2 = pk2(0.f);
        #pragma unroll
        for (int j = 0; j < 4; ++j)
            pd2 = __builtin_elementwise_fma(x0[j], Qxq[j], pd2);
        const float pd0  = oct_reduce(pd2.x + pd2.y);
        const float den0 = fmaf(sig, pd0, lf.x);
        const float s0   = sig * rcp_nr(den0);

        // ---- a, bb chains (group-1 data), then c2 (group-2 data) ----
        f2 a2 = pk2(0.f), bb2 = pk2(0.f);
        #pragma unroll
        for (int j = 0; j < 4; ++j) {
            a2  = __builtin_elementwise_fma(x1[j], xQq[j], a2);
            bb2 = __builtin_elementwise_fma(x1[j], Qxq[j], bb2);
        }
        const float a  = oct_reduce(a2.x + a2.y);
        const float bb = oct_reduce(bb2.x + bb2.y);

        f2 c22 = pk2(0.f);
        #pragma unroll
        for (int j = 0; j < 4; ++j)
            c22 = __builtin_elementwise_fma(x1[j], uq[j], c22);
        const float c2 = oct_reduce(c22.x + c22.y);

        // ---- scalars (R19 op order, batch-uniform across all threads) ----
        const float err0 = dd.x - wy0S;
        const float es0  = s0 * err0;
        const float sa   = s0 * a;
        const float sb   = s0 * bb;

        const float sig1 = sig * lf.y;
        const float pd1  = fmaf(-sa, bb, c2);
        const float den1 = fmaf(sig1, pd1, lf.z);
        const float s1   = sig1 * rcp_nr(den1);
        const float y1   = fmaf(es0, bb, wy1S);
        const float err1 = dd.y - y1;
        const float es1  = s1 * err1;
        sig = sig1 * lf.w;

        if (tid == 0)
            *(float2*)(y_out + (size_t)b * N_ + t) = make_float2(wy0S, y1);

        // ---- dual rank-1 updates fused with next-dots (R19 structure;
        //      QT==Q^T preserved: shared broadcast scalars, sign-symmetric
        //      products — independent of reduction order) ----
        const float qx1r = fmaf(-sa, qxrS, urS);
        const float xq1r = fmaf(-sb, xqrS, vrS);
        const f2 nsa   = pk2(-sa);
        const f2 nsb   = pk2(-sb);
        const f2 s0v   = pk2(s0);
        const f2 s1v   = pk2(s1);
        const f2 es0v  = pk2(es0);
        const f2 es1v  = pk2(es1);
        const f2 ntr0  = pk2(-(s0 * qxrS));
        const f2 ntr1  = pk2(-(s1 * qx1r));
        const f2 nxqr  = pk2(-xqrS);
        const f2 nxq1r = pk2(-xq1r);

        f2 nqx = pk2(0.f), nxq = pk2(0.f), nu = pk2(0.f), nv = pk2(0.f);
        f2 nw0 = pk2(0.f), nw1 = pk2(0.f);

        #pragma unroll
        for (int j = 0; j < 4; ++j) {
            const f2 Qx1 = __builtin_elementwise_fma(nsa, Qxq[j], uq[j]);
            const f2 xQ1 = __builtin_elementwise_fma(nsb, xQq[j], vq[j]);
            const f2 tq0 = s0v * Qxq[j];
            const f2 tq1 = s1v * Qx1;
            // w: two honest rank-1 adds
            w[j] = __builtin_elementwise_fma(Qxq[j], es0v, w[j]);
            w[j] = __builtin_elementwise_fma(Qx1,    es1v, w[j]);
            // Q row r: subtract both outer-product terms
            Q[j] = __builtin_elementwise_fma(ntr0, xQq[j], Q[j]);
            Q[j] = __builtin_elementwise_fma(ntr1, xQ1,    Q[j]);
            // QT row r (= Q column r): transposed products, identical bits
            QT[j] = __builtin_elementwise_fma(tq0, nxqr,  QT[j]);
            QT[j] = __builtin_elementwise_fma(tq1, nxq1r, QT[j]);
            // fused next-round pre-dots on the freshly updated registers
            if (fuse) {
                nqx = __builtin_elementwise_fma(Q[j],  xn0[j], nqx);
                nxq = __builtin_elementwise_fma(QT[j], xn0[j], nxq);
                nu  = __builtin_elementwise_fma(Q[j],  xn1[j], nu);
                nv  = __builtin_elementwise_fma(QT[j], xn1[j], nv);
                nw0 = __builtin_elementwise_fma(w[j],  xn0[j], nw0);
                nw1 = __builtin_elementwise_fma(w[j],  xn1[j], nw1);
            }
        }

        if (fuse) {
            qxrS = oct_reduce(nqx.x + nqx.y);
            xqrS = oct_reduce(nxq.x + nxq.y);
            urS  = oct_reduce(nu.x + nu.y);
            vrS  = oct_reduce(nv.x + nv.y);
            if (q8 < 4)
                bufs[par ^ 1][q8][r] =
                    (q8 == 0) ? qxrS : (q8 == 1) ? xqrS : (q8 == 2) ? urS : vrS;
            wy0S = oct_reduce(nw0.x + nw0.y);
            wy1S = oct_reduce(nw1.x + nw1.y);
        }
    };

    // main loop: rounds k=0..995 (t=0..1990), 4-round unroll for pair rotation.
    for (int t = 0; t < 1992; t += 8) {
        round(t + 0, P0a, P0b, P1a, P1b, P3a, P3b, 0, true, true);
        round(t + 2, P1a, P1b, P2a, P2b, P0a, P0b, 1, true, true);
        round(t + 4, P2a, P2b, P3a, P3b, P1a, P1b, 0, true, true);
        round(t + 6, P3a, P3b, P0a, P0b, P2a, P2b, 1, true, true);
    }
    // tail (same flags as R19)
    round(1992, P0a, P0b, P1a, P1b, P3a, P3b, 0, true,  true);
    round(1994, P1a, P1b, P2a, P2b, P0a, P0b, 1, false, true);
    round(1996, P2a, P2b, P3a, P3b, P1a, P1b, 0, false, true);
    round(1998, P3a, P3b, P0a, P0b, P2a, P2b, 1, false, false);

    // ---- final weights: row-group 0 (threads 0..7) holds a full replica ----
    if (r == 0) {
        float4* wo = (float4*)(w_out + (size_t)b * TAPS_ + cb);
        #pragma unroll
        for (int j4 = 0; j4 < 2; ++j4)
            wo[j4] = make_float4(w[2*j4].x, w[2*j4].y, w[2*j4+1].x, w[2*j4+1].y);
    }
}

extern "C" void kernel_launch(void* const* d_in, const int* in_sizes, int n_in,
                              void* d_out, int out_size, void* d_ws, size_t ws_size,
                              hipStream_t stream) {
    const float* x_seq   = (const float*)d_in[0];
    const float* d_seq   = (const float*)d_in[1];
    const float* lambdas = (const float*)d_in[2];

    float* y_out = (float*)d_out;                      // B*N floats
    float* w_out = (float*)d_out + (size_t)B_ * N_;    // B*TAPS floats

    rls_kernel<<<B_, 512, 0, stream>>>(x_seq, d_seq, lambdas, y_out, w_out);
}